// Round 4
// baseline (119.684 us; speedup 1.0000x reference)
//
#include <hip/hip_runtime.h>
#include <hip/hip_bf16.h>

#define ALPHA 0.2f
#define NROW 8192
#define JB 256
#define NSTEP (NROW/JB)

typedef __attribute__((ext_vector_type(4))) float f4;
typedef __attribute__((ext_vector_type(8))) short s8;

__device__ __forceinline__ short f2bf_bits(float x){
    __hip_bfloat16 b = __float2bfloat16(x);
    return __builtin_bit_cast(short, b);
}

__device__ __forceinline__ void gload_lds16(const void* g, void* l){
    __builtin_amdgcn_global_load_lds(
        (const __attribute__((address_space(1))) void*)g,
        (__attribute__((address_space(3))) void*)l, 16, 0, 0);
}

// K1: h = x@W ; s1 ; s2 ; F1=exp(s2) ; F2=exp(0.2*s2) ; hT[f][i] = bf16(h[i][f])
__global__ __launch_bounds__(256) void k_proj(
    const float* __restrict__ x, const float* __restrict__ W, const float* __restrict__ a,
    float* __restrict__ s1, float* __restrict__ s2,
    float* __restrict__ F1, float* __restrict__ F2, __hip_bfloat16* __restrict__ hT)
{
    __shared__ float Wsh[128*64];
    __shared__ float xsh[4*128];
    const int t = threadIdx.x;
    const int f = t & 63, ry = t >> 6;
    const int row0 = blockIdx.x * 4;
    for (int i = t; i < 128*64; i += 256) Wsh[i] = W[i];
    for (int i = t; i < 4*128; i += 256) xsh[i] = x[row0*128 + i];
    __syncthreads();
    float acc = 0.f;
    #pragma unroll
    for (int k = 0; k < 128; ++k) acc = fmaf(xsh[ry*128 + k], Wsh[k*64 + f], acc);
    float p1 = acc * a[f], p2 = acc * a[64 + f];
    #pragma unroll
    for (int m = 32; m; m >>= 1){ p1 += __shfl_xor(p1, m, 64); p2 += __shfl_xor(p2, m, 64); }
    const int row = row0 + ry;
    if (f == 0){
        s1[row] = p1; s2[row] = p2;
        F1[row] = __expf(p2); F2[row] = __expf(0.2f * p2);
    }
    hT[f * NROW + row] = __float2bfloat16(acc);
}

// K2: s2max = max(s2)
__global__ __launch_bounds__(256) void k_s2max(const float* __restrict__ s2, float* __restrict__ s2max)
{
    __shared__ float red[256];
    float m = -1e30f;
    for (int i = threadIdx.x; i < NROW; i += 256) m = fmaxf(m, s2[i]);
    red[threadIdx.x] = m; __syncthreads();
    for (int s = 128; s; s >>= 1){
        if (threadIdx.x < (unsigned)s) red[threadIdx.x] = fmaxf(red[threadIdx.x], red[threadIdx.x + s]);
        __syncthreads();
    }
    if (threadIdx.x == 0) s2max[0] = red[0];
}

// K3: adj streamed HBM->LDS via global_load_lds, 2-deep prefetch with COUNTED
// vmcnt (never drain-0 in the loop), raw s_barrier pairs. F1/F2/hT read from
// L2 into registers. Factored softmax (no exp in loop), PV via bf16 MFMA.
__global__ __launch_bounds__(512, 4) void k_attn3(
    const float* __restrict__ adj, const float* __restrict__ s1g,
    const float* __restrict__ s2maxp, const float* __restrict__ F1g,
    const float* __restrict__ F2g, const __hip_bfloat16* __restrict__ hT,
    float* __restrict__ out)
{
    __shared__ float adjT[2][16][JB];   // 32 KB; phys unit u of row c holds logical unit u^(c&7)
    __shared__ float accb[8][16][64];   // 32 KB
    __shared__ float lsb[8][16];

    const int tid  = threadIdx.x;
    const int w    = tid >> 6, lane = tid & 63;
    const int lr   = lane & 15;     // A-row / C-col
    const int hi   = lane >> 4;     // k-group 0..3
    const int i0   = blockIdx.x * 16;
    const int row  = i0 + lr;

    const float s1r = s1g[row];
    const float t0  = s1r + s2maxp[0];
    const float Mr  = fmaxf(t0, ALPHA * t0);      // >= true row max of lrelu logits
    const float E1  = __expf(s1r - Mr);           // t>0 branch:  p = E1*F1_j
    const float E2  = __expf(ALPHA * s1r - Mr);   // t<=0 branch: p = E2*F2_j
    const float T1  = __expf(-s1r);               // cond (t>0) <=> F1_j > T1

    const int c0 = w*2, c1 = w*2 + 1;
    const float* adjr0 = adj + (long)(i0 + c0)*NROW + ((lane ^ (c0 & 7)) << 2);
    const float* adjr1 = adj + (long)(i0 + c1)*NROW + ((lane ^ (c1 & 7)) << 2);

// exactly 2 vm-ops per wave per STAGE -> per-wave vmcnt counting is uniform
#define STAGE(b, js) do { \
    const long j0s = (long)(js) * JB; \
    gload_lds16(adjr0 + j0s, &adjT[b][c0][0]); \
    gload_lds16(adjr1 + j0s, &adjT[b][c1][0]); \
} while(0)

    STAGE(0, 0);
    STAGE(1, 1);

    f4 acc0 = {0.f,0.f,0.f,0.f}, acc1 = {0.f,0.f,0.f,0.f};
    f4 acc2 = {0.f,0.f,0.f,0.f}, acc3 = {0.f,0.f,0.f,0.f};
    float lsum = 0.f;

    const int vbase = w*8 + hi*2;   // logical 16B-unit within row
    const int sw    = lr & 7;
    const int fo    = w*32 + hi*8;

    for (int t = 0; t < NSTEP; ++t){
        const int b = t & 1;
        // staging(t) complete; staging(t+1)'s 2 ops may stay in flight
        if (t < NSTEP - 1) asm volatile("s_waitcnt vmcnt(2)" ::: "memory");
        else               asm volatile("s_waitcnt vmcnt(0)" ::: "memory");
        __builtin_amdgcn_s_barrier();

        const int j0 = t * JB;
        // hT B-fragments + F factors (L2-resident) into registers
        const __hip_bfloat16* hq = hT + lr*NROW + j0 + fo;
        s8 h0 = *(const s8*)(hq);
        s8 h1 = *(const s8*)(hq + 16*NROW);
        s8 h2 = *(const s8*)(hq + 32*NROW);
        s8 h3 = *(const s8*)(hq + 48*NROW);
        const float* f1p = F1g + j0 + fo;
        const float* f2p = F2g + j0 + fo;
        f4 f1a = *(const f4*)(f1p), f1b = *(const f4*)(f1p + 4);
        f4 f2a = *(const f4*)(f2p), f2b = *(const f4*)(f2p + 4);

        // adj fragment from LDS (XOR-swizzled slots)
        f4 a0 = *(const f4*)&adjT[b][lr][(( vbase      ^ sw) << 2)];
        f4 a1 = *(const f4*)&adjT[b][lr][(((vbase + 1) ^ sw) << 2)];

        float q0,q1,q2,q3,q4,q5,q6,q7;
#define CALC(av, g1, g2, qd) { \
        float fz = ((g1) > T1) ? (g1)*E1 : (g2)*E2; \
        qd = ((av) > 0.f) ? fz : 0.f; }
        CALC(a0[0], f1a[0], f2a[0], q0); CALC(a0[1], f1a[1], f2a[1], q1);
        CALC(a0[2], f1a[2], f2a[2], q2); CALC(a0[3], f1a[3], f2a[3], q3);
        CALC(a1[0], f1b[0], f2b[0], q4); CALC(a1[1], f1b[1], f2b[1], q5);
        CALC(a1[2], f1b[2], f2b[2], q6); CALC(a1[3], f1b[3], f2b[3], q7);
#undef CALC
        lsum += ((q0+q1)+(q2+q3)) + ((q4+q5)+(q6+q7));

        s8 af;
        af[0]=f2bf_bits(q0); af[1]=f2bf_bits(q1); af[2]=f2bf_bits(q2); af[3]=f2bf_bits(q3);
        af[4]=f2bf_bits(q4); af[5]=f2bf_bits(q5); af[6]=f2bf_bits(q6); af[7]=f2bf_bits(q7);
        acc0 = __builtin_amdgcn_mfma_f32_16x16x32_bf16(af, h0, acc0, 0, 0, 0);
        acc1 = __builtin_amdgcn_mfma_f32_16x16x32_bf16(af, h1, acc1, 0, 0, 0);
        acc2 = __builtin_amdgcn_mfma_f32_16x16x32_bf16(af, h2, acc2, 0, 0, 0);
        acc3 = __builtin_amdgcn_mfma_f32_16x16x32_bf16(af, h3, acc3, 0, 0, 0);

        if (t + 2 < NSTEP){
            __builtin_amdgcn_s_barrier();   // all waves done reading buf b
            STAGE(b, t + 2);                // restage b; stays in flight across next barrier
        }
    }
#undef STAGE

    lsum += __shfl_xor(lsum, 16, 64);
    lsum += __shfl_xor(lsum, 32, 64);

    // C layout: col = lane&15, row = (lane>>4)*4 + reg
    #pragma unroll
    for (int r = 0; r < 4; ++r){
        accb[w][hi*4 + r][ 0 + lr] = acc0[r];
        accb[w][hi*4 + r][16 + lr] = acc1[r];
        accb[w][hi*4 + r][32 + lr] = acc2[r];
        accb[w][hi*4 + r][48 + lr] = acc3[r];
    }
    if (lane < 16) lsb[w][lane] = lsum;
    __syncthreads();

    for (int idx = tid; idx < 16*64; idx += 512){
        int r = idx >> 6, cf = idx & 63;
        float s = 0.f, L = 0.f;
        #pragma unroll
        for (int ww = 0; ww < 8; ++ww){ s += accb[ww][r][cf]; L += lsb[ww][r]; }
        float v = s / L;
        out[(long)(i0 + r)*64 + cf] = (v > 0.f) ? v : expm1f(v);
    }
}

extern "C" void kernel_launch(void* const* d_in, const int* in_sizes, int n_in,
                              void* d_out, int out_size, void* d_ws, size_t ws_size,
                              hipStream_t stream)
{
    const float* x   = (const float*)d_in[0];
    const float* adj = (const float*)d_in[1];
    const float* W   = (const float*)d_in[2];
    const float* a   = (const float*)d_in[3];
    float* out = (float*)d_out;

    char* ws = (char*)d_ws;
    float* s1   = (float*)(ws);                    // 32 KB
    float* s2   = (float*)(ws + 32768);            // 32 KB
    float* F1   = (float*)(ws + 65536);            // 32 KB
    float* F2   = (float*)(ws + 98304);            // 32 KB
    float* s2mx = (float*)(ws + 131072);           // 256 B
    __hip_bfloat16* hT = (__hip_bfloat16*)(ws + 131328);   // 1 MB

    k_proj <<<2048, 256, 0, stream>>>(x, W, a, s1, s2, F1, F2, hT);
    k_s2max<<<   1, 256, 0, stream>>>(s2, s2mx);
    k_attn3<<< 512, 512, 0, stream>>>(adj, s1, s2mx, F1, F2, hT, out);
}

// Round 5
// 118.442 us; speedup vs baseline: 1.0105x; 1.0105x over previous
//
#include <hip/hip_runtime.h>
#include <hip/hip_bf16.h>

#define ALPHA 0.2f
#define NROW 8192
#define JW   32
#define NST  32     // steps per wave (1024 / 32)

typedef __attribute__((ext_vector_type(4))) float f4;
typedef __attribute__((ext_vector_type(8))) short s8;

__device__ __forceinline__ short f2bf_bits(float x){
    __hip_bfloat16 b = __float2bfloat16(x);
    return __builtin_bit_cast(short, b);
}

__device__ __forceinline__ void gload_lds16(const void* g, void* l){
    __builtin_amdgcn_global_load_lds(
        (const __attribute__((address_space(1))) void*)g,
        (__attribute__((address_space(3))) void*)l, 16, 0, 0);
}

// K1: h = x@W ; s1 ; s2 ; F1=exp(s2) ; F2=exp(0.2*s2) ; hT[f][i] = bf16(h[i][f])
__global__ __launch_bounds__(256) void k_proj(
    const float* __restrict__ x, const float* __restrict__ W, const float* __restrict__ a,
    float* __restrict__ s1, float* __restrict__ s2,
    float* __restrict__ F1, float* __restrict__ F2, __hip_bfloat16* __restrict__ hT)
{
    __shared__ float Wsh[128*64];
    __shared__ float xsh[4*128];
    const int t = threadIdx.x;
    const int f = t & 63, ry = t >> 6;
    const int row0 = blockIdx.x * 4;
    for (int i = t; i < 128*64; i += 256) Wsh[i] = W[i];
    for (int i = t; i < 4*128; i += 256) xsh[i] = x[row0*128 + i];
    __syncthreads();
    float acc = 0.f;
    #pragma unroll
    for (int k = 0; k < 128; ++k) acc = fmaf(xsh[ry*128 + k], Wsh[k*64 + f], acc);
    float p1 = acc * a[f], p2 = acc * a[64 + f];
    #pragma unroll
    for (int m = 32; m; m >>= 1){ p1 += __shfl_xor(p1, m, 64); p2 += __shfl_xor(p2, m, 64); }
    const int row = row0 + ry;
    if (f == 0){
        s1[row] = p1; s2[row] = p2;
        F1[row] = __expf(p2); F2[row] = __expf(0.2f * p2);
    }
    hT[f * NROW + row] = __float2bfloat16(acc);
}

// K2: s2max = max(s2)
__global__ __launch_bounds__(1024) void k_s2max(const float* __restrict__ s2, float* __restrict__ s2max)
{
    __shared__ float red[1024];
    float m = -1e30f;
    for (int i = threadIdx.x; i < NROW; i += 1024) m = fmaxf(m, s2[i]);
    red[threadIdx.x] = m; __syncthreads();
    for (int s = 512; s; s >>= 1){
        if (threadIdx.x < (unsigned)s) red[threadIdx.x] = fmaxf(red[threadIdx.x], red[threadIdx.x + s]);
        __syncthreads();
    }
    if (threadIdx.x == 0) s2max[0] = red[0];
}

// K3: barrier-free per-wave pipeline. Each wave: private LDS triple-buffer for
// its adj tile ([16][32] floats, XOR-swizzled), counted vmcnt(4) per step
// (counts ONLY own staging), hF register loads double-buffered one step ahead.
__global__ __launch_bounds__(512, 4) void k_attn4(
    const float* __restrict__ adj, const float* __restrict__ s1g,
    const float* __restrict__ s2maxp, const float* __restrict__ F1g,
    const float* __restrict__ F2g, const __hip_bfloat16* __restrict__ hT,
    float* __restrict__ out)
{
    __shared__ __attribute__((aligned(128))) char arena[49152]; // 8 waves x 3 bufs x 2KB; reused for epilogue

    const int tid = threadIdx.x;
    const int w = tid >> 6, lane = tid & 63;
    const int lr = lane & 15, hi = lane >> 4;
    const int i0 = blockIdx.x * 16, row = i0 + lr;

    const float s1r = s1g[row];
    const float t0 = s1r + s2maxp[0];
    const float Mr = fmaxf(t0, ALPHA * t0);      // >= true row max of lrelu logits
    const float E1 = __expf(s1r - Mr);           // t>0:  p = E1*F1_j
    const float E2 = __expf(ALPHA * s1r - Mr);   // t<=0: p = E2*F2_j
    const float T1 = __expf(-s1r);               // (t>0) <=> F1_j > T1

    const int jw = w * 1024;
    const int rsub = lane >> 3;                  // 0..7
    const int usw  = (lane & 7) ^ rsub;          // pre-swizzled source unit
    const float* src0 = adj + (long)(i0 + rsub) * NROW + jw + usw * 4;
    const float* src1 = src0 + 8 * (long)NROW;
    char* wb = arena + w * 6144;

    const __hip_bfloat16* hq0 = hT + lr * NROW + jw + hi * 8;
    const float* f1p = F1g + jw + hi * 8;
    const float* f2p = F2g + jw + hi * 8;

    const int rdofs0 = lr * 128 + (((2 * hi    ) ^ (lr & 7)) << 4);
    const int rdofs1 = lr * 128 + (((2 * hi + 1) ^ (lr & 7)) << 4);

    f4 acc0 = {0.f,0.f,0.f,0.f}, acc1 = {0.f,0.f,0.f,0.f};
    f4 acc2 = {0.f,0.f,0.f,0.f}, acc3 = {0.f,0.f,0.f,0.f};
    float lsum = 0.f;

    s8 h0A,h1A,h2A,h3A, h0B,h1B,h2B,h3B;
    f4 f1aA,f1bA,f2aA,f2bA, f1aB,f1bB,f2aB,f2bB;

#define LOADHF(S, s) do { \
    const __hip_bfloat16* hq_ = hq0 + (s) * JW; \
    h0##S = *(const s8*)(hq_); \
    h1##S = *(const s8*)(hq_ + 16 * NROW); \
    h2##S = *(const s8*)(hq_ + 32 * NROW); \
    h3##S = *(const s8*)(hq_ + 48 * NROW); \
    const float* f1_ = f1p + (s) * JW; \
    const float* f2_ = f2p + (s) * JW; \
    f1a##S = *(const f4*)(f1_); f1b##S = *(const f4*)(f1_ + 4); \
    f2a##S = *(const f4*)(f2_); f2b##S = *(const f4*)(f2_ + 4); \
} while(0)

#define STAGE(bofs, s) do { \
    gload_lds16(src0 + (s) * JW, wb + (bofs)); \
    gload_lds16(src1 + (s) * JW, wb + (bofs) + 1024); \
} while(0)

#define CALCQ(av, g1, g2, qd) { \
    float fz = ((g1) > T1) ? (g1) * E1 : (g2) * E2; \
    qd = ((av) > 0.f) ? fz : 0.f; }

#define STEPC(S, bofs) do { \
    f4 a0 = *(const f4*)(wb + (bofs) + rdofs0); \
    f4 a1 = *(const f4*)(wb + (bofs) + rdofs1); \
    float q0,q1,q2,q3,q4,q5,q6,q7; \
    CALCQ(a0[0], f1a##S[0], f2a##S[0], q0); CALCQ(a0[1], f1a##S[1], f2a##S[1], q1); \
    CALCQ(a0[2], f1a##S[2], f2a##S[2], q2); CALCQ(a0[3], f1a##S[3], f2a##S[3], q3); \
    CALCQ(a1[0], f1b##S[0], f2b##S[0], q4); CALCQ(a1[1], f1b##S[1], f2b##S[1], q5); \
    CALCQ(a1[2], f1b##S[2], f2b##S[2], q6); CALCQ(a1[3], f1b##S[3], f2b##S[3], q7); \
    lsum += ((q0+q1)+(q2+q3)) + ((q4+q5)+(q6+q7)); \
    s8 af; \
    af[0]=f2bf_bits(q0); af[1]=f2bf_bits(q1); af[2]=f2bf_bits(q2); af[3]=f2bf_bits(q3); \
    af[4]=f2bf_bits(q4); af[5]=f2bf_bits(q5); af[6]=f2bf_bits(q6); af[7]=f2bf_bits(q7); \
    acc0 = __builtin_amdgcn_mfma_f32_16x16x32_bf16(af, h0##S, acc0, 0, 0, 0); \
    acc1 = __builtin_amdgcn_mfma_f32_16x16x32_bf16(af, h1##S, acc1, 0, 0, 0); \
    acc2 = __builtin_amdgcn_mfma_f32_16x16x32_bf16(af, h2##S, acc2, 0, 0, 0); \
    acc3 = __builtin_amdgcn_mfma_f32_16x16x32_bf16(af, h3##S, acc3, 0, 0, 0); \
} while(0)

    // prologue: hF FIRST (older than staging -> first wait keeps S(1),S(2) in flight)
    LOADHF(A, 0);
    STAGE(0, 0); STAGE(2048, 1); STAGE(4096, 2);

    int b0 = 0, b1 = 2048, b2 = 4096;
    for (int s = 0; s < NST; s += 2){
        // staging(s) + hF(s) complete; staging(s+1),(s+2) stay in flight
        asm volatile("s_waitcnt vmcnt(4)" ::: "memory");
        LOADHF(B, s + 1);
        STEPC(A, b0);
        __builtin_amdgcn_sched_barrier(0);   // pin: hF(B) issued BEFORE next STAGE
        if (s + 3 < NST) STAGE(b0, s + 3);

        asm volatile("s_waitcnt vmcnt(4)" ::: "memory");
        if (s + 2 < NST) LOADHF(A, s + 2);
        STEPC(B, b1);
        __builtin_amdgcn_sched_barrier(0);
        if (s + 4 < NST) STAGE(b1, s + 4);

        int tmp = b2; b2 = b1; b1 = b0; b0 = tmp;
    }
#undef LOADHF
#undef STAGE
#undef CALCQ
#undef STEPC

    lsum += __shfl_xor(lsum, 16, 64);
    lsum += __shfl_xor(lsum, 32, 64);

    __syncthreads();   // all waves done streaming -> repurpose arena
    float* accb = (float*)arena;               // [8][16][64]
    float* lsb  = (float*)(arena + 32768);     // [8][16]

    // C layout: col = lane&15, row = (lane>>4)*4 + reg
    #pragma unroll
    for (int r = 0; r < 4; ++r){
        accb[((w*16 + hi*4 + r) << 6) +  0 + lr] = acc0[r];
        accb[((w*16 + hi*4 + r) << 6) + 16 + lr] = acc1[r];
        accb[((w*16 + hi*4 + r) << 6) + 32 + lr] = acc2[r];
        accb[((w*16 + hi*4 + r) << 6) + 48 + lr] = acc3[r];
    }
    if (lane < 16) lsb[w*16 + lane] = lsum;
    __syncthreads();

    for (int idx = tid; idx < 1024; idx += 512){
        int r = idx >> 6, cf = idx & 63;
        float sa = 0.f, L = 0.f;
        #pragma unroll
        for (int ww = 0; ww < 8; ++ww){
            sa += accb[((ww*16 + r) << 6) + cf];
            L  += lsb[ww*16 + r];
        }
        float v = sa / L;
        out[(long)(i0 + r) * 64 + cf] = (v > 0.f) ? v : expm1f(v);
    }
}

extern "C" void kernel_launch(void* const* d_in, const int* in_sizes, int n_in,
                              void* d_out, int out_size, void* d_ws, size_t ws_size,
                              hipStream_t stream)
{
    const float* x   = (const float*)d_in[0];
    const float* adj = (const float*)d_in[1];
    const float* W   = (const float*)d_in[2];
    const float* a   = (const float*)d_in[3];
    float* out = (float*)d_out;

    char* ws = (char*)d_ws;
    float* s1   = (float*)(ws);                    // 32 KB
    float* s2   = (float*)(ws + 32768);            // 32 KB
    float* F1   = (float*)(ws + 65536);            // 32 KB
    float* F2   = (float*)(ws + 98304);            // 32 KB
    float* s2mx = (float*)(ws + 131072);           // 256 B
    __hip_bfloat16* hT = (__hip_bfloat16*)(ws + 131328);   // 1 MB

    k_proj <<<2048,  256, 0, stream>>>(x, W, a, s1, s2, F1, F2, hT);
    k_s2max<<<   1, 1024, 0, stream>>>(s2, s2mx);
    k_attn4<<< 512,  512, 0, stream>>>(adj, s1, s2mx, F1, F2, hT, out);
}